// Round 10
// baseline (410.073 us; speedup 1.0000x reference)
//
#include <hip/hip_runtime.h>
#include <hip/hip_bf16.h>
#include <cmath>

// Problem constants: B=8, DIM=128, T=16, H*W=1024, INNER=256, UP2=512,
// NH=4, DH=64, K=4, Bx=8192 sequences, S=16.

typedef __attribute__((ext_vector_type(8))) short short8;
typedef __attribute__((ext_vector_type(4))) short short4v;
typedef __attribute__((ext_vector_type(4))) float f32x4;
typedef unsigned short ushort_t;

static __device__ __forceinline__ float siluf(float v) {
  return v / (1.0f + __expf(-v));
}
static __device__ __forceinline__ float logsigf(float v) {
  return fminf(v, 0.f) - log1pf(__expf(-fabsf(v)));
}
static __device__ __forceinline__ float sel4(float4 w, int idx) {
  float r = w.x;
  r = (idx == 1) ? w.y : r;
  r = (idx == 2) ? w.z : r;
  r = (idx == 3) ? w.w : r;
  return r;
}
static __device__ __forceinline__ ushort_t f2bf(float x) {   // RNE fp32->bf16
  unsigned u = __float_as_uint(x);
  return (ushort_t)((u + 0x7fffu + ((u >> 16) & 1u)) >> 16);
}
static __device__ __forceinline__ float bf2f(ushort_t h) {
  return __uint_as_float(((unsigned)h) << 16);
}
// HW packed RNE fp32->bf16 (v_cvt_pk_bf16_f32); bit-identical to f2bf for
// normal values, ~3x fewer VALU ops.
static __device__ __forceinline__ ushort2 pk2bf(float a, float b) {
  union { __hip_bfloat162 v; ushort2 u; } cv;
  cv.v = __float22bfloat162_rn(make_float2(a, b));
  return cv.u;
}
// Quad-perm DPP replacements for __shfl_xor(x, 1/2/3): VALU-speed lane
// permutation (no ds_swizzle / lgkmcnt in the dependency chain).
// quad_perm ctrl: xor1=[1,0,3,2]=0xB1, xor2=[2,3,0,1]=0x4E, xor3=[3,2,1,0]=0x1B.
#define DPPF(x, ctrl) \
  __int_as_float(__builtin_amdgcn_mov_dpp(__float_as_int(x), (ctrl), 0xF, 0xF, true))

// ---------------------------------------------------------------------------
// Prep: weight fragments.
//  wt_hi/lo [j][c]   (512x128)  from Wup[c][j]      (up GEMM B-operand)
//  wdt_hi/lo [c][j]  (128x256)  from Wd[j][c]       (down GEMM A-operand)
//  wgf [24][64][8]   bf16       gate-GEMM B-fragments: B[k=ch][n], n<4 = ig
//                    head n, 4<=n<8 = fg head n-4, n>=8 zero.
// ---------------------------------------------------------------------------
__global__ __launch_bounds__(256)
void prep_w(const float* __restrict__ Wup, const float* __restrict__ Wd,
            const float* __restrict__ igw, const float* __restrict__ fgw,
            ushort_t* __restrict__ wt_hi, ushort_t* __restrict__ wt_lo,
            ushort_t* __restrict__ wdt_hi, ushort_t* __restrict__ wdt_lo,
            ushort_t* __restrict__ wgf)
{
  const int g = blockIdx.x * 256 + threadIdx.x;
  if (g < 65536) {                      // g = c*512 + j
    const int c = g >> 9, j = g & 511;
    const float w = Wup[g];
    const ushort_t h = f2bf(w);
    wt_hi[j*128 + c] = h;
    wt_lo[j*128 + c] = f2bf(w - bf2f(h));
  } else if (g < 98304) {               // g2 = j*128 + c
    const int g2 = g - 65536;
    const int j = g2 >> 7, c = g2 & 127;
    const float w = Wd[g2];
    const ushort_t h = f2bf(w);
    wdt_hi[c*256 + j] = h;
    wdt_lo[c*256 + j] = f2bf(w - bf2f(h));
  } else if (g < 110592) {              // gate fragments
    const int e = g - 98304;            // e = kc*512 + lane*8 + i
    const int kc = e >> 9;
    const int lane = (e >> 3) & 63;
    const int i = e & 7;
    const int n = lane & 15;
    const int kq = kc*32 + (lane >> 4)*8 + i;
    float val = 0.f;
    if (n < 4)      val = igw[kq*4 + n];
    else if (n < 8) val = fgw[kq*4 + (n - 4)];
    wgf[e] = f2bf(val);
  }
}

// ---------------------------------------------------------------------------
// Phase 1: up-projection via split-bf16 MFMA — R5 version verbatim
// (132.7 us best measured; R0-R6 established this is a robust local floor:
// traffic, VALU work, wave count, VGPR pressure all shown non-binding).
// ---------------------------------------------------------------------------
#define AS 72   // LDS row stride in bf16 (64 + 8 pad)

__global__ __launch_bounds__(256, 3)
void up_gemm(const float* __restrict__ x,
             const ushort_t* __restrict__ wt_hi, const ushort_t* __restrict__ wt_lo,
             ushort_t* __restrict__ xmb, ushort_t* __restrict__ szb)
{
  __shared__ ushort_t sAhi[128*AS];
  __shared__ ushort_t sAlo[128*AS];

  const int tid = threadIdx.x;
  const int hw0 = blockIdx.x * 128;
  const int j0  = blockIdx.y * 128;
  const int bt  = blockIdx.z;
  const int b   = bt >> 4, t = bt & 15;

  const int wv = tid >> 6;
  const int wm = wv >> 1, wn = wv & 1;
  const int ln = tid & 63;
  const int lm = ln & 15;
  const int q  = ln >> 4;

  const int hwL = tid & 127;
  const int cg  = tid >> 7;

  f32x4 acc[4][4];
  #pragma unroll
  for (int i = 0; i < 4; ++i)
    #pragma unroll
    for (int k = 0; k < 4; ++k) acc[i][k] = (f32x4){0.f, 0.f, 0.f, 0.f};

  for (int stage = 0; stage < 2; ++stage) {
    // --- batched staging: issue all 32 loads, then convert ---
    float xv[8][4];
    {
      const float* xb = &x[((b*128 + stage*64)*16 + t)*1024 + hw0 + hwL];
      #pragma unroll
      for (int p = 0; p < 8; ++p) {
        const float* xp = xb + (p*8 + cg*4)*16384;
        xv[p][0] = xp[0];
        xv[p][1] = xp[16384];
        xv[p][2] = xp[32768];
        xv[p][3] = xp[49152];
      }
    }
    #pragma unroll
    for (int p = 0; p < 8; ++p) {
      const int cl = p*8 + cg*4;
      const float v0 = xv[p][0], v1 = xv[p][1], v2 = xv[p][2], v3 = xv[p][3];
      const ushort2 h01 = pk2bf(v0, v1);
      const ushort2 h23 = pk2bf(v2, v3);
      const ushort2 l01 = pk2bf(v0 - bf2f(h01.x), v1 - bf2f(h01.y));
      const ushort2 l23 = pk2bf(v2 - bf2f(h23.x), v3 - bf2f(h23.y));
      *(ushort4*)&sAhi[hwL*AS + cl] = make_ushort4(h01.x, h01.y, h23.x, h23.y);
      *(ushort4*)&sAlo[hwL*AS + cl] = make_ushort4(l01.x, l01.y, l23.x, l23.y);
    }
    __syncthreads();

    #pragma unroll
    for (int s = 0; s < 2; ++s) {
      const int kc = s*32 + q*8;
      const int kg = stage*64 + kc;
      short8 bh[4], bl[4];
      #pragma unroll
      for (int nt = 0; nt < 4; ++nt) {
        const int jr = j0 + wn*64 + nt*16 + lm;
        bh[nt] = *(const short8*)&wt_hi[jr*128 + kg];
        bl[nt] = *(const short8*)&wt_lo[jr*128 + kg];
      }
      #pragma unroll
      for (int mt = 0; mt < 4; ++mt) {
        const int ao = (wm*64 + mt*16 + lm)*AS + kc;
        const short8 ah = *(const short8*)&sAhi[ao];
        const short8 al = *(const short8*)&sAlo[ao];
        #pragma unroll
        for (int nt = 0; nt < 4; ++nt) {
          acc[mt][nt] = __builtin_amdgcn_mfma_f32_16x16x32_bf16(ah, bh[nt], acc[mt][nt], 0, 0, 0);
          acc[mt][nt] = __builtin_amdgcn_mfma_f32_16x16x32_bf16(ah, bl[nt], acc[mt][nt], 0, 0, 0);
          acc[mt][nt] = __builtin_amdgcn_mfma_f32_16x16x32_bf16(al, bh[nt], acc[mt][nt], 0, 0, 0);
        }
      }
    }
    __syncthreads();
  }

  // --- epilogue: direct stores (fastest measured path) ---
  const bool isz = (j0 >= 256);
  #pragma unroll
  for (int mt = 0; mt < 4; ++mt) {
    #pragma unroll
    for (int nt = 0; nt < 4; ++nt) {
      const int jc = j0 + wn*64 + nt*16 + lm;
      #pragma unroll
      for (int r = 0; r < 4; ++r) {
        const int rowg = bt*1024 + hw0 + wm*64 + mt*16 + q*4 + r;
        const float v = acc[mt][nt][r];
        if (!isz) xmb[rowg*256 + jc] = f2bf(v);
        else      szb[rowg*256 + (jc - 256)] = f2bf(siluf(v));
      }
    }
  }
}

// ---------------------------------------------------------------------------
// Phase 2: fused conv + qkv + gates + mLSTM + LN + skip — R8 version
// verbatim (DPP quad-perm + 8-deep load pipeline; contributed the R8 win).
// ---------------------------------------------------------------------------
#define SQ 264    // q/k/v row stride (bf16): 528 B -> 2-way banks (free), 16B-aligned rows
#define SXC 260   // xc row stride (bf16), scalar access only

__global__ __launch_bounds__(256, 4)
void seq_kernel(const ushort_t* __restrict__ xm_ws,
                ushort_t* szh,                    // silu(z) in, h_state out
                const float* __restrict__ conv_w, const float* __restrict__ conv_b,
                const float* __restrict__ Wq, const float* __restrict__ Wk,
                const float* __restrict__ Wv,
                const ushort_t* __restrict__ wgf,
                const float* __restrict__ igb, const float* __restrict__ fgb,
                const float* __restrict__ lnw, const float* __restrict__ skipw)
{
  __shared__ __align__(16) ushort_t q_lds[16*SQ];
  __shared__ __align__(16) ushort_t k_lds[16*SQ];
  __shared__ __align__(16) ushort_t v_lds[16*SQ];
  __shared__ __align__(16) ushort_t xc_lds[16*SXC];
  __shared__ __align__(16) ushort_t p_lds[4*16*36];   // P[h][s][t], stride 36
  __shared__ __align__(16) float s_gpart[512];        // [w][t][8]; later aliased s_lfc[17][4]
  __shared__ float s_ig[64];                          // [t][h]
  __shared__ float s_lf[64];                          // [t][h]

  const int tid = threadIdx.x;
  const int j   = tid;
  const int l2  = j & 3;
  const int seq = blockIdx.x;
  const int rbase = (seq >> 10) * 16384 + (seq & 1023);

  const int w    = tid >> 6;      // wave = head
  const int ln   = tid & 63;
  const int g    = ln >> 4;       // 16-lane group
  const int lc   = ln & 15;       // lane-in-group (MFMA col / A-row)
  const int hb2  = w * 64;

  // --- weights for headwise qkv (lane-permuted for quad shuffles) ---
  const float4 wq4 = *(const float4*)&Wq[j*4];
  const float4 wk4 = *(const float4*)&Wk[j*4];
  const float4 wv4 = *(const float4*)&Wv[j*4];
  float wqp[4], wkp[4], wvp[4];
  #pragma unroll
  for (int d = 0; d < 4; ++d) {
    const int idx = l2 ^ d;
    wqp[d] = sel4(wq4, idx);
    wkp[d] = sel4(wk4, idx);
    wvp[d] = sel4(wv4, idx);
  }
  const float cw0 = conv_w[j],     cw1 = conv_w[256+j];
  const float cw2 = conv_w[512+j], cw3 = conv_w[768+j];
  const float cb  = conv_b[j];

  // --- Phase A: conv + silu + headwise q,k,v ; 8-deep load pipeline ---
  ushort_t mh[8];
  #pragma unroll
  for (int t = 0; t < 8; ++t)
    mh[t] = xm_ws[(rbase + t*1024)*256 + j];

  float p1 = 0.f, p2 = 0.f, p3 = 0.f;
  #pragma unroll
  for (int t = 0; t < 16; ++t) {
    const float m = bf2f(mh[t & 7]);
    if (t < 8) mh[t & 7] = xm_ws[(rbase + (t+8)*1024)*256 + j];  // refill slot
    const float pre = cw0*p3 + cw1*p2 + cw2*p1 + cw3*m + cb;
    const float x = siluf(pre);
    p3 = p2; p2 = p1; p1 = m;
    const float x1 = DPPF(x, 0xB1), x2 = DPPF(x, 0x4E), x3 = DPPF(x, 0x1B);
    const float m1 = DPPF(m, 0xB1), m2 = DPPF(m, 0x4E), m3 = DPPF(m, 0x1B);
    const float qv = x*wqp[0] + x1*wqp[1] + x2*wqp[2] + x3*wqp[3];
    const float kv = x*wkp[0] + x1*wkp[1] + x2*wkp[2] + x3*wkp[3];
    const float vv = m*wvp[0] + m1*wvp[1] + m2*wvp[2] + m3*wvp[3];
    q_lds [t*SQ  + j] = f2bf(qv);
    k_lds [t*SQ  + j] = f2bf(kv);
    v_lds [t*SQ  + j] = f2bf(vv);
    xc_lds[t*SXC + j] = f2bf(x);
  }
  __syncthreads();   // B1

  // --- Gates via MFMA: Y[16t x 768] * W[768 x 8(+8 pad)], K-split by wave ---
  f32x4 gacc = (f32x4){0.f, 0.f, 0.f, 0.f};
  #pragma unroll
  for (int c6 = 0; c6 < 6; ++c6) {
    const int kc = w*6 + c6;                        // global K-chunk (wave-uniform)
    const ushort_t* yb = (kc < 8) ? q_lds : (kc < 16) ? k_lds : v_lds;
    const int klocal = (kc & 7)*32;
    const short8 ya = *(const short8*)&yb[lc*SQ + klocal + g*8];
    const short8 wb = *(const short8*)&wgf[(kc*64 + ln)*8];
    gacc = __builtin_amdgcn_mfma_f32_16x16x32_bf16(ya, wb, gacc, 0, 0, 0);
  }
  // QK^T via MFMA (needs only q,k of own head; independent of gates)
  f32x4 qkacc = (f32x4){0.f, 0.f, 0.f, 0.f};
  {
    const short8 qa0 = *(const short8*)&q_lds[lc*SQ + hb2 + g*8];
    const short8 qa1 = *(const short8*)&q_lds[lc*SQ + hb2 + 32 + g*8];
    const short8 kb0 = *(const short8*)&k_lds[lc*SQ + hb2 + g*8];
    const short8 kb1 = *(const short8*)&k_lds[lc*SQ + hb2 + 32 + g*8];
    qkacc = __builtin_amdgcn_mfma_f32_16x16x32_bf16(qa0, kb0, qkacc, 0, 0, 0);
    qkacc = __builtin_amdgcn_mfma_f32_16x16x32_bf16(qa1, kb1, qkacc, 0, 0, 0);
  }
  // store gate partials (cols 0..7 valid)
  if (lc < 8) {
    #pragma unroll
    for (int r = 0; r < 4; ++r)
      s_gpart[w*128 + (g*4 + r)*8 + lc] = gacc[r];
  }
  __syncthreads();   // B2

  // --- finalize gates: sum 4 wave-partials, bias, logsig ---
  if (tid < 128) {
    const int t = tid >> 3, n = tid & 7;
    const float s = s_gpart[t*8+n] + s_gpart[128 + t*8+n]
                  + s_gpart[256 + t*8+n] + s_gpart[384 + t*8+n];
    if (n < 4) s_ig[t*4 + n] = s + igb[n];
    else       s_lf[t*4 + (n-4)] = logsigf(s + fgb[n-4]);
  }
  __syncthreads();   // B3

  float* s_lfc = s_gpart;        // alias (gpart dead): [17][4]
  if (tid < 4) {
    float run = 0.f;
    s_lfc[tid] = 0.f;
    #pragma unroll
    for (int t = 0; t < 16; ++t) { run += s_lf[t*4 + tid]; s_lfc[(t+1)*4 + tid] = run; }
  }
  __syncthreads();   // B4

  // --- decay + normalizer in C-layout: lane holds rows s=g*4+r, col t=lc ---
  {
    const int tcol = lc;
    const float lfc_t1 = s_lfc[(tcol+1)*4 + w];
    const float igt    = s_ig[tcol*4 + w];
    float ld[4], mloc[4];
    #pragma unroll
    for (int r = 0; r < 4; ++r) {
      const int s = g*4 + r;
      const float lfs = s_lfc[(s+1)*4 + w];
      ld[r] = (tcol <= s) ? (lfs - lfc_t1 + igt) : -INFINITY;
      mloc[r] = ld[r];
    }
    #pragma unroll
    for (int off = 1; off < 16; off <<= 1) {
      #pragma unroll
      for (int r = 0; r < 4; ++r) mloc[r] = fmaxf(mloc[r], __shfl_xor(mloc[r], off));
    }
    float cs[4], rsum[4];
    #pragma unroll
    for (int r = 0; r < 4; ++r) {
      const int s = g*4 + r;
      cs[r] = (tcol <= s) ? (qkacc[r] * 0.125f) * __expf(ld[r] - mloc[r]) : 0.f;
      rsum[r] = cs[r];
    }
    #pragma unroll
    for (int off = 1; off < 16; off <<= 1) {
      #pragma unroll
      for (int r = 0; r < 4; ++r) rsum[r] += __shfl_xor(rsum[r], off);
    }
    #pragma unroll
    for (int r = 0; r < 4; ++r) {
      const float denom = fmaxf(fabsf(rsum[r]), __expf(-mloc[r])) + 1e-6f;
      const float pv = cs[r] / denom;
      p_lds[(w*16 + g*4 + r)*36 + tcol] = f2bf(pv);
    }
  }
  __syncthreads();   // B5

  // --- PV via MFMA: O[16s x 64d] = P[16 x 32pad] x V[32pad x 64] ---
  f32x4 oacc[4];
  #pragma unroll
  for (int c = 0; c < 4; ++c) oacc[c] = (f32x4){0.f, 0.f, 0.f, 0.f};
  {
    const int tb = g*8;
    short8 pa = (short8){0,0,0,0,0,0,0,0};
    if (tb < 16) {
      const short4v plo = *(const short4v*)&p_lds[(w*16 + lc)*36 + tb];
      const short4v phi = *(const short4v*)&p_lds[(w*16 + lc)*36 + tb + 4];
      pa[0]=plo[0]; pa[1]=plo[1]; pa[2]=plo[2]; pa[3]=plo[3];
      pa[4]=phi[0]; pa[5]=phi[1]; pa[6]=phi[2]; pa[7]=phi[3];
    }
    #pragma unroll
    for (int c = 0; c < 4; ++c) {
      short8 vb;
      #pragma unroll
      for (int i = 0; i < 8; ++i)
        vb[i] = (short)v_lds[((tb + i) & 15)*SQ + hb2 + c*16 + lc];  // garbage ok when tb>=16 (A=0)
      oacc[c] = __builtin_amdgcn_mfma_f32_16x16x32_bf16(pa, vb, oacc[c], 0, 0, 0);
    }
  }

  // --- LN over DH=64 + epilogue; lane holds O[s=g*4+r][d=c*16+lc] ---
  float lnc[4], skc[4];
  #pragma unroll
  for (int c = 0; c < 4; ++c) {
    const int ch = hb2 + c*16 + lc;
    lnc[c] = lnw[ch];
    skc[c] = skipw[ch];
  }
  #pragma unroll
  for (int r = 0; r < 4; ++r) {
    const int s = g*4 + r;
    float tot = oacc[0][r] + oacc[1][r] + oacc[2][r] + oacc[3][r];
    #pragma unroll
    for (int off = 1; off < 16; off <<= 1) tot += __shfl_xor(tot, off);
    const float mu = tot * (1.f/64.f);
    float var = 0.f;
    #pragma unroll
    for (int c = 0; c < 4; ++c) { const float d = oacc[c][r] - mu; var += d*d; }
    #pragma unroll
    for (int off = 1; off < 16; off <<= 1) var += __shfl_xor(var, off);
    const float rstd = rsqrtf(var * (1.f/64.f) + 1e-5f);
    #pragma unroll
    for (int c = 0; c < 4; ++c) {
      const int ch = hb2 + c*16 + lc;
      const float hn = (oacc[c][r] - mu) * rstd * lnc[c];
      const float xcv = bf2f(xc_lds[s*SXC + ch]);
      q_lds[s*SQ + ch] = f2bf(hn + skc[c]*xcv);   // q_lds dead since B2; own-wave cols
    }
  }
  __syncthreads();   // B6: publish h-part

  // --- coalesced RMW pass: thread owns column ch=tid for all 16 rows ---
  #pragma unroll
  for (int s = 0; s < 16; ++s) {
    const long long og = (long long)(rbase + s*1024)*256 + tid;
    const float szv = bf2f(szh[og]);
    const float hv  = bf2f(q_lds[s*SQ + tid]);
    szh[og] = f2bf(hv * szv);
  }
}

// ---------------------------------------------------------------------------
// Phase 3: down-projection, split-bf16 MFMA.
// R9: dispatch-tail fix. Old grid 1024 blocks @3/CU = 768 concurrent ->
// 1.33 rounds (25% tail at 1 blk/CU with no latency hiding). New: hw-split
// 128->64, grid 16x1x128 = 2048 blocks, acc[4][2]=32 VGPR (total ~60, fits
// the 64-cap) -> (256,4) -> 1024 concurrent -> exactly 2.0 rounds, no tail.
// No staging/barriers here, so the R6 per-block-fixed-cost regression
// mechanism doesn't apply. Per-output K-order (kc asc, hi-then-lo)
// preserved -> bit-identical numerics. B-loads per instr: 16 rows x 64B
// full lines; out stores unchanged 64B-segment coalesced.
// ---------------------------------------------------------------------------
__global__ __launch_bounds__(256, 4)
void down_gemm(const ushort_t* __restrict__ hb,
               const ushort_t* __restrict__ wdt_hi, const ushort_t* __restrict__ wdt_lo,
               float* __restrict__ out)
{
  const int tid = threadIdx.x;
  const int hw0 = blockIdx.x * 64;
  const int bt  = blockIdx.z;
  const int bq  = bt >> 4, tq = bt & 15;
  const int rowbase = bt*1024 + hw0;

  const int wv = tid >> 6;
  const int wm = wv >> 1, wn = wv & 1;   // wm: c-half (2x64), wn: hw-half (2x32)
  const int ln = tid & 63;
  const int lm = ln & 15;
  const int q  = ln >> 4;

  f32x4 acc[4][2];
  #pragma unroll
  for (int i = 0; i < 4; ++i)
    #pragma unroll
    for (int k = 0; k < 2; ++k) acc[i][k] = (f32x4){0.f, 0.f, 0.f, 0.f};

  #pragma unroll 2
  for (int kc = 0; kc < 256; kc += 32) {
    const int kq = kc + q*8;
    short8 bf[2];
    #pragma unroll
    for (int nt = 0; nt < 2; ++nt) {
      const int n = wn*32 + nt*16 + lm;
      bf[nt] = *(const short8*)&hb[(rowbase + n)*256 + kq];
    }
    #pragma unroll
    for (int mt = 0; mt < 4; ++mt) {
      const int c = wm*64 + mt*16 + lm;
      const short8 ah = *(const short8*)&wdt_hi[c*256 + kq];
      const short8 al = *(const short8*)&wdt_lo[c*256 + kq];
      #pragma unroll
      for (int nt = 0; nt < 2; ++nt) {
        acc[mt][nt] = __builtin_amdgcn_mfma_f32_16x16x32_bf16(ah, bf[nt], acc[mt][nt], 0, 0, 0);
        acc[mt][nt] = __builtin_amdgcn_mfma_f32_16x16x32_bf16(al, bf[nt], acc[mt][nt], 0, 0, 0);
      }
    }
  }

  #pragma unroll
  for (int mt = 0; mt < 4; ++mt) {
    #pragma unroll
    for (int nt = 0; nt < 2; ++nt) {
      const int hw = hw0 + wn*32 + nt*16 + lm;
      #pragma unroll
      for (int r = 0; r < 4; ++r) {
        const int c = wm*64 + mt*16 + q*4 + r;
        out[((bq*128 + c)*16 + tq)*1024 + hw] = acc[mt][nt][r];
      }
    }
  }
}

// ---------------------------------------------------------------------------
extern "C" void kernel_launch(void* const* d_in, const int* in_sizes, int n_in,
                              void* d_out, int out_size, void* d_ws, size_t ws_size,
                              hipStream_t stream)
{
  const float* x      = (const float*)d_in[0];
  const float* Wup    = (const float*)d_in[1];
  const float* conv_w = (const float*)d_in[2];
  const float* conv_b = (const float*)d_in[3];
  const float* Wq     = (const float*)d_in[4];
  const float* Wk     = (const float*)d_in[5];
  const float* Wv     = (const float*)d_in[6];
  const float* igw    = (const float*)d_in[7];
  const float* igb    = (const float*)d_in[8];
  const float* fgw    = (const float*)d_in[9];
  const float* fgb    = (const float*)d_in[10];
  const float* lnw    = (const float*)d_in[11];
  const float* skipw  = (const float*)d_in[12];
  const float* Wd     = (const float*)d_in[13];
  float* out = (float*)d_out;

  // ws layout: xmb bf16 [131072][256] = 64 MB; szb bf16 = 64 MB (silu(z) in,
  // h_state out); then weight fragments (~0.4 MB).
  ushort_t* xmb    = (ushort_t*)d_ws;
  ushort_t* szb    = xmb + 33554432;
  ushort_t* wt_hi  = (ushort_t*)((char*)d_ws + 134217728);
  ushort_t* wt_lo  = wt_hi + 65536;
  ushort_t* wdt_hi = wt_lo + 65536;
  ushort_t* wdt_lo = wdt_hi + 32768;
  ushort_t* wgf    = wdt_lo + 32768;    // 24*64*8 = 12288 bf16

  prep_w<<<432, 256, 0, stream>>>(Wup, Wd, igw, fgw,
                                  wt_hi, wt_lo, wdt_hi, wdt_lo, wgf);
  up_gemm<<<dim3(8, 4, 128), 256, 0, stream>>>(x, wt_hi, wt_lo, xmb, szb);
  seq_kernel<<<8192, 256, 0, stream>>>(xmb, szb,
                                       conv_w, conv_b, Wq, Wk, Wv,
                                       wgf, igb, fgb, lnw, skipw);
  down_gemm<<<dim3(16, 1, 128), 256, 0, stream>>>(szb, wdt_hi, wdt_lo, out);
}

// Round 11
// 369.563 us; speedup vs baseline: 1.1096x; 1.1096x over previous
//
#include <hip/hip_runtime.h>
#include <hip/hip_bf16.h>
#include <cmath>

// Problem constants: B=8, DIM=128, T=16, H*W=1024, INNER=256, UP2=512,
// NH=4, DH=64, K=4, Bx=8192 sequences, S=16.

typedef __attribute__((ext_vector_type(8))) short short8;
typedef __attribute__((ext_vector_type(4))) short short4v;
typedef __attribute__((ext_vector_type(4))) float f32x4;
typedef unsigned short ushort_t;

static __device__ __forceinline__ float siluf(float v) {
  return v / (1.0f + __expf(-v));
}
static __device__ __forceinline__ float logsigf(float v) {
  return fminf(v, 0.f) - log1pf(__expf(-fabsf(v)));
}
static __device__ __forceinline__ float sel4(float4 w, int idx) {
  float r = w.x;
  r = (idx == 1) ? w.y : r;
  r = (idx == 2) ? w.z : r;
  r = (idx == 3) ? w.w : r;
  return r;
}
static __device__ __forceinline__ ushort_t f2bf(float x) {   // RNE fp32->bf16
  unsigned u = __float_as_uint(x);
  return (ushort_t)((u + 0x7fffu + ((u >> 16) & 1u)) >> 16);
}
static __device__ __forceinline__ float bf2f(ushort_t h) {
  return __uint_as_float(((unsigned)h) << 16);
}
// HW packed RNE fp32->bf16 (v_cvt_pk_bf16_f32); bit-identical to f2bf for
// normal values, ~3x fewer VALU ops.
static __device__ __forceinline__ ushort2 pk2bf(float a, float b) {
  union { __hip_bfloat162 v; ushort2 u; } cv;
  cv.v = __float22bfloat162_rn(make_float2(a, b));
  return cv.u;
}
// DPP lane-exchange replacements for __shfl_xor (VALU-speed, no ds_swizzle
// / lgkmcnt in the dependency chain). quad_perm: xor1=0xB1, xor2=0x4E,
// xor3=0x1B. row_ror:8 (0x128) == xor8 within each 16-lane row
// ((i+-8) mod 16 == i^8, rotation direction immaterial). No DPP for xor4.
#define DPPF(x, ctrl) \
  __int_as_float(__builtin_amdgcn_mov_dpp(__float_as_int(x), (ctrl), 0xF, 0xF, true))

// ---------------------------------------------------------------------------
// Prep: weight fragments.
//  wt_hi/lo [j][c]   (512x128)  from Wup[c][j]      (up GEMM B-operand)
//  wdt_hi/lo [c][j]  (128x256)  from Wd[j][c]       (down GEMM A-operand)
//  wgf [24][64][8]   bf16       gate-GEMM B-fragments: B[k=ch][n], n<4 = ig
//                    head n, 4<=n<8 = fg head n-4, n>=8 zero.
// R10: output-major index mapping -> coalesced 2B writes (were 2B scattered
// at 256B stride); reads become scattered 4B but Wup/Wd are L2-resident.
// Same values to same destinations -> numerics unchanged.
// ---------------------------------------------------------------------------
__global__ __launch_bounds__(256)
void prep_w(const float* __restrict__ Wup, const float* __restrict__ Wd,
            const float* __restrict__ igw, const float* __restrict__ fgw,
            ushort_t* __restrict__ wt_hi, ushort_t* __restrict__ wt_lo,
            ushort_t* __restrict__ wdt_hi, ushort_t* __restrict__ wdt_lo,
            ushort_t* __restrict__ wgf)
{
  const int g = blockIdx.x * 256 + threadIdx.x;
  if (g < 65536) {                      // g = j*128 + c (output-major)
    const int jj = g >> 7, c = g & 127;
    const float w = Wup[c*512 + jj];
    const ushort_t h = f2bf(w);
    wt_hi[g] = h;
    wt_lo[g] = f2bf(w - bf2f(h));
  } else if (g < 98304) {               // g2 = c*256 + j (output-major)
    const int g2 = g - 65536;
    const int c = g2 >> 8, jj = g2 & 255;
    const float w = Wd[jj*128 + c];
    const ushort_t h = f2bf(w);
    wdt_hi[g2] = h;
    wdt_lo[g2] = f2bf(w - bf2f(h));
  } else if (g < 110592) {              // gate fragments
    const int e = g - 98304;            // e = kc*512 + lane*8 + i
    const int kc = e >> 9;
    const int lane = (e >> 3) & 63;
    const int i = e & 7;
    const int n = lane & 15;
    const int kq = kc*32 + (lane >> 4)*8 + i;
    float val = 0.f;
    if (n < 4)      val = igw[kq*4 + n];
    else if (n < 8) val = fgw[kq*4 + (n - 4)];
    wgf[e] = f2bf(val);
  }
}

// ---------------------------------------------------------------------------
// Phase 1: up-projection via split-bf16 MFMA — R5 version verbatim
// (132.7 us best measured; R0-R6 established this is a robust local floor:
// traffic, VALU work, wave count, VGPR pressure all shown non-binding).
// ---------------------------------------------------------------------------
#define AS 72   // LDS row stride in bf16 (64 + 8 pad)

__global__ __launch_bounds__(256, 3)
void up_gemm(const float* __restrict__ x,
             const ushort_t* __restrict__ wt_hi, const ushort_t* __restrict__ wt_lo,
             ushort_t* __restrict__ xmb, ushort_t* __restrict__ szb)
{
  __shared__ ushort_t sAhi[128*AS];
  __shared__ ushort_t sAlo[128*AS];

  const int tid = threadIdx.x;
  const int hw0 = blockIdx.x * 128;
  const int j0  = blockIdx.y * 128;
  const int bt  = blockIdx.z;
  const int b   = bt >> 4, t = bt & 15;

  const int wv = tid >> 6;
  const int wm = wv >> 1, wn = wv & 1;
  const int ln = tid & 63;
  const int lm = ln & 15;
  const int q  = ln >> 4;

  const int hwL = tid & 127;
  const int cg  = tid >> 7;

  f32x4 acc[4][4];
  #pragma unroll
  for (int i = 0; i < 4; ++i)
    #pragma unroll
    for (int k = 0; k < 4; ++k) acc[i][k] = (f32x4){0.f, 0.f, 0.f, 0.f};

  for (int stage = 0; stage < 2; ++stage) {
    // --- batched staging: issue all 32 loads, then convert ---
    float xv[8][4];
    {
      const float* xb = &x[((b*128 + stage*64)*16 + t)*1024 + hw0 + hwL];
      #pragma unroll
      for (int p = 0; p < 8; ++p) {
        const float* xp = xb + (p*8 + cg*4)*16384;
        xv[p][0] = xp[0];
        xv[p][1] = xp[16384];
        xv[p][2] = xp[32768];
        xv[p][3] = xp[49152];
      }
    }
    #pragma unroll
    for (int p = 0; p < 8; ++p) {
      const int cl = p*8 + cg*4;
      const float v0 = xv[p][0], v1 = xv[p][1], v2 = xv[p][2], v3 = xv[p][3];
      const ushort2 h01 = pk2bf(v0, v1);
      const ushort2 h23 = pk2bf(v2, v3);
      const ushort2 l01 = pk2bf(v0 - bf2f(h01.x), v1 - bf2f(h01.y));
      const ushort2 l23 = pk2bf(v2 - bf2f(h23.x), v3 - bf2f(h23.y));
      *(ushort4*)&sAhi[hwL*AS + cl] = make_ushort4(h01.x, h01.y, h23.x, h23.y);
      *(ushort4*)&sAlo[hwL*AS + cl] = make_ushort4(l01.x, l01.y, l23.x, l23.y);
    }
    __syncthreads();

    #pragma unroll
    for (int s = 0; s < 2; ++s) {
      const int kc = s*32 + q*8;
      const int kg = stage*64 + kc;
      short8 bh[4], bl[4];
      #pragma unroll
      for (int nt = 0; nt < 4; ++nt) {
        const int jr = j0 + wn*64 + nt*16 + lm;
        bh[nt] = *(const short8*)&wt_hi[jr*128 + kg];
        bl[nt] = *(const short8*)&wt_lo[jr*128 + kg];
      }
      #pragma unroll
      for (int mt = 0; mt < 4; ++mt) {
        const int ao = (wm*64 + mt*16 + lm)*AS + kc;
        const short8 ah = *(const short8*)&sAhi[ao];
        const short8 al = *(const short8*)&sAlo[ao];
        #pragma unroll
        for (int nt = 0; nt < 4; ++nt) {
          acc[mt][nt] = __builtin_amdgcn_mfma_f32_16x16x32_bf16(ah, bh[nt], acc[mt][nt], 0, 0, 0);
          acc[mt][nt] = __builtin_amdgcn_mfma_f32_16x16x32_bf16(ah, bl[nt], acc[mt][nt], 0, 0, 0);
          acc[mt][nt] = __builtin_amdgcn_mfma_f32_16x16x32_bf16(al, bh[nt], acc[mt][nt], 0, 0, 0);
        }
      }
    }
    __syncthreads();
  }

  // --- epilogue: direct stores (fastest measured path) ---
  const bool isz = (j0 >= 256);
  #pragma unroll
  for (int mt = 0; mt < 4; ++mt) {
    #pragma unroll
    for (int nt = 0; nt < 4; ++nt) {
      const int jc = j0 + wn*64 + nt*16 + lm;
      #pragma unroll
      for (int r = 0; r < 4; ++r) {
        const int rowg = bt*1024 + hw0 + wm*64 + mt*16 + q*4 + r;
        const float v = acc[mt][nt][r];
        if (!isz) xmb[rowg*256 + jc] = f2bf(v);
        else      szb[rowg*256 + (jc - 256)] = f2bf(siluf(v));
      }
    }
  }
}

// ---------------------------------------------------------------------------
// Phase 2: fused conv + qkv + gates + mLSTM + LN + skip — R8 structure
// (DPP quad-perm + 8-deep load pipeline in Phase A). R10 adds: DPP for the
// butterfly reduction stages off=1,2 (quad_perm) and off=8 (row_ror:8);
// off=4 stays __shfl_xor (no DPP xor4). Same stage order & pairings ->
// bit-identical results; removes 48 ds_swizzles from serial chains.
// ---------------------------------------------------------------------------
#define SQ 264    // q/k/v row stride (bf16): 528 B -> 2-way banks (free), 16B-aligned rows
#define SXC 260   // xc row stride (bf16), scalar access only

__global__ __launch_bounds__(256, 4)
void seq_kernel(const ushort_t* __restrict__ xm_ws,
                ushort_t* szh,                    // silu(z) in, h_state out
                const float* __restrict__ conv_w, const float* __restrict__ conv_b,
                const float* __restrict__ Wq, const float* __restrict__ Wk,
                const float* __restrict__ Wv,
                const ushort_t* __restrict__ wgf,
                const float* __restrict__ igb, const float* __restrict__ fgb,
                const float* __restrict__ lnw, const float* __restrict__ skipw)
{
  __shared__ __align__(16) ushort_t q_lds[16*SQ];
  __shared__ __align__(16) ushort_t k_lds[16*SQ];
  __shared__ __align__(16) ushort_t v_lds[16*SQ];
  __shared__ __align__(16) ushort_t xc_lds[16*SXC];
  __shared__ __align__(16) ushort_t p_lds[4*16*36];   // P[h][s][t], stride 36
  __shared__ __align__(16) float s_gpart[512];        // [w][t][8]; later aliased s_lfc[17][4]
  __shared__ float s_ig[64];                          // [t][h]
  __shared__ float s_lf[64];                          // [t][h]

  const int tid = threadIdx.x;
  const int j   = tid;
  const int l2  = j & 3;
  const int seq = blockIdx.x;
  const int rbase = (seq >> 10) * 16384 + (seq & 1023);

  const int w    = tid >> 6;      // wave = head
  const int ln   = tid & 63;
  const int g    = ln >> 4;       // 16-lane group
  const int lc   = ln & 15;       // lane-in-group (MFMA col / A-row)
  const int hb2  = w * 64;

  // --- weights for headwise qkv (lane-permuted for quad shuffles) ---
  const float4 wq4 = *(const float4*)&Wq[j*4];
  const float4 wk4 = *(const float4*)&Wk[j*4];
  const float4 wv4 = *(const float4*)&Wv[j*4];
  float wqp[4], wkp[4], wvp[4];
  #pragma unroll
  for (int d = 0; d < 4; ++d) {
    const int idx = l2 ^ d;
    wqp[d] = sel4(wq4, idx);
    wkp[d] = sel4(wk4, idx);
    wvp[d] = sel4(wv4, idx);
  }
  const float cw0 = conv_w[j],     cw1 = conv_w[256+j];
  const float cw2 = conv_w[512+j], cw3 = conv_w[768+j];
  const float cb  = conv_b[j];

  // --- Phase A: conv + silu + headwise q,k,v ; 8-deep load pipeline ---
  ushort_t mh[8];
  #pragma unroll
  for (int t = 0; t < 8; ++t)
    mh[t] = xm_ws[(rbase + t*1024)*256 + j];

  float p1 = 0.f, p2 = 0.f, p3 = 0.f;
  #pragma unroll
  for (int t = 0; t < 16; ++t) {
    const float m = bf2f(mh[t & 7]);
    if (t < 8) mh[t & 7] = xm_ws[(rbase + (t+8)*1024)*256 + j];  // refill slot
    const float pre = cw0*p3 + cw1*p2 + cw2*p1 + cw3*m + cb;
    const float x = siluf(pre);
    p3 = p2; p2 = p1; p1 = m;
    const float x1 = DPPF(x, 0xB1), x2 = DPPF(x, 0x4E), x3 = DPPF(x, 0x1B);
    const float m1 = DPPF(m, 0xB1), m2 = DPPF(m, 0x4E), m3 = DPPF(m, 0x1B);
    const float qv = x*wqp[0] + x1*wqp[1] + x2*wqp[2] + x3*wqp[3];
    const float kv = x*wkp[0] + x1*wkp[1] + x2*wkp[2] + x3*wkp[3];
    const float vv = m*wvp[0] + m1*wvp[1] + m2*wvp[2] + m3*wvp[3];
    q_lds [t*SQ  + j] = f2bf(qv);
    k_lds [t*SQ  + j] = f2bf(kv);
    v_lds [t*SQ  + j] = f2bf(vv);
    xc_lds[t*SXC + j] = f2bf(x);
  }
  __syncthreads();   // B1

  // --- Gates via MFMA: Y[16t x 768] * W[768 x 8(+8 pad)], K-split by wave ---
  f32x4 gacc = (f32x4){0.f, 0.f, 0.f, 0.f};
  #pragma unroll
  for (int c6 = 0; c6 < 6; ++c6) {
    const int kc = w*6 + c6;                        // global K-chunk (wave-uniform)
    const ushort_t* yb = (kc < 8) ? q_lds : (kc < 16) ? k_lds : v_lds;
    const int klocal = (kc & 7)*32;
    const short8 ya = *(const short8*)&yb[lc*SQ + klocal + g*8];
    const short8 wb = *(const short8*)&wgf[(kc*64 + ln)*8];
    gacc = __builtin_amdgcn_mfma_f32_16x16x32_bf16(ya, wb, gacc, 0, 0, 0);
  }
  // QK^T via MFMA (needs only q,k of own head; independent of gates)
  f32x4 qkacc = (f32x4){0.f, 0.f, 0.f, 0.f};
  {
    const short8 qa0 = *(const short8*)&q_lds[lc*SQ + hb2 + g*8];
    const short8 qa1 = *(const short8*)&q_lds[lc*SQ + hb2 + 32 + g*8];
    const short8 kb0 = *(const short8*)&k_lds[lc*SQ + hb2 + g*8];
    const short8 kb1 = *(const short8*)&k_lds[lc*SQ + hb2 + 32 + g*8];
    qkacc = __builtin_amdgcn_mfma_f32_16x16x32_bf16(qa0, kb0, qkacc, 0, 0, 0);
    qkacc = __builtin_amdgcn_mfma_f32_16x16x32_bf16(qa1, kb1, qkacc, 0, 0, 0);
  }
  // store gate partials (cols 0..7 valid)
  if (lc < 8) {
    #pragma unroll
    for (int r = 0; r < 4; ++r)
      s_gpart[w*128 + (g*4 + r)*8 + lc] = gacc[r];
  }
  __syncthreads();   // B2

  // --- finalize gates: sum 4 wave-partials, bias, logsig ---
  if (tid < 128) {
    const int t = tid >> 3, n = tid & 7;
    const float s = s_gpart[t*8+n] + s_gpart[128 + t*8+n]
                  + s_gpart[256 + t*8+n] + s_gpart[384 + t*8+n];
    if (n < 4) s_ig[t*4 + n] = s + igb[n];
    else       s_lf[t*4 + (n-4)] = logsigf(s + fgb[n-4]);
  }
  __syncthreads();   // B3

  float* s_lfc = s_gpart;        // alias (gpart dead): [17][4]
  if (tid < 4) {
    float run = 0.f;
    s_lfc[tid] = 0.f;
    #pragma unroll
    for (int t = 0; t < 16; ++t) { run += s_lf[t*4 + tid]; s_lfc[(t+1)*4 + tid] = run; }
  }
  __syncthreads();   // B4

  // --- decay + normalizer in C-layout: lane holds rows s=g*4+r, col t=lc ---
  {
    const int tcol = lc;
    const float lfc_t1 = s_lfc[(tcol+1)*4 + w];
    const float igt    = s_ig[tcol*4 + w];
    float ld[4], mloc[4];
    #pragma unroll
    for (int r = 0; r < 4; ++r) {
      const int s = g*4 + r;
      const float lfs = s_lfc[(s+1)*4 + w];
      ld[r] = (tcol <= s) ? (lfs - lfc_t1 + igt) : -INFINITY;
      mloc[r] = ld[r];
    }
    // butterfly max over 16-lane groups: stages 1,2,4,8 (1,2,8 via DPP)
    #pragma unroll
    for (int r = 0; r < 4; ++r) {
      mloc[r] = fmaxf(mloc[r], DPPF(mloc[r], 0xB1));
      mloc[r] = fmaxf(mloc[r], DPPF(mloc[r], 0x4E));
      mloc[r] = fmaxf(mloc[r], __shfl_xor(mloc[r], 4));
      mloc[r] = fmaxf(mloc[r], DPPF(mloc[r], 0x128));
    }
    float cs[4], rsum[4];
    #pragma unroll
    for (int r = 0; r < 4; ++r) {
      const int s = g*4 + r;
      cs[r] = (tcol <= s) ? (qkacc[r] * 0.125f) * __expf(ld[r] - mloc[r]) : 0.f;
      rsum[r] = cs[r];
    }
    // butterfly sum, same stage order as before -> bit-identical
    #pragma unroll
    for (int r = 0; r < 4; ++r) {
      rsum[r] += DPPF(rsum[r], 0xB1);
      rsum[r] += DPPF(rsum[r], 0x4E);
      rsum[r] += __shfl_xor(rsum[r], 4);
      rsum[r] += DPPF(rsum[r], 0x128);
    }
    #pragma unroll
    for (int r = 0; r < 4; ++r) {
      const float denom = fmaxf(fabsf(rsum[r]), __expf(-mloc[r])) + 1e-6f;
      const float pv = cs[r] / denom;
      p_lds[(w*16 + g*4 + r)*36 + tcol] = f2bf(pv);
    }
  }
  __syncthreads();   // B5

  // --- PV via MFMA: O[16s x 64d] = P[16 x 32pad] x V[32pad x 64] ---
  f32x4 oacc[4];
  #pragma unroll
  for (int c = 0; c < 4; ++c) oacc[c] = (f32x4){0.f, 0.f, 0.f, 0.f};
  {
    const int tb = g*8;
    short8 pa = (short8){0,0,0,0,0,0,0,0};
    if (tb < 16) {
      const short4v plo = *(const short4v*)&p_lds[(w*16 + lc)*36 + tb];
      const short4v phi = *(const short4v*)&p_lds[(w*16 + lc)*36 + tb + 4];
      pa[0]=plo[0]; pa[1]=plo[1]; pa[2]=plo[2]; pa[3]=plo[3];
      pa[4]=phi[0]; pa[5]=phi[1]; pa[6]=phi[2]; pa[7]=phi[3];
    }
    #pragma unroll
    for (int c = 0; c < 4; ++c) {
      short8 vb;
      #pragma unroll
      for (int i = 0; i < 8; ++i)
        vb[i] = (short)v_lds[((tb + i) & 15)*SQ + hb2 + c*16 + lc];  // garbage ok when tb>=16 (A=0)
      oacc[c] = __builtin_amdgcn_mfma_f32_16x16x32_bf16(pa, vb, oacc[c], 0, 0, 0);
    }
  }

  // --- LN over DH=64 + epilogue; lane holds O[s=g*4+r][d=c*16+lc] ---
  float lnc[4], skc[4];
  #pragma unroll
  for (int c = 0; c < 4; ++c) {
    const int ch = hb2 + c*16 + lc;
    lnc[c] = lnw[ch];
    skc[c] = skipw[ch];
  }
  #pragma unroll
  for (int r = 0; r < 4; ++r) {
    const int s = g*4 + r;
    float tot = oacc[0][r] + oacc[1][r] + oacc[2][r] + oacc[3][r];
    tot += DPPF(tot, 0xB1);
    tot += DPPF(tot, 0x4E);
    tot += __shfl_xor(tot, 4);
    tot += DPPF(tot, 0x128);
    const float mu = tot * (1.f/64.f);
    float var = 0.f;
    #pragma unroll
    for (int c = 0; c < 4; ++c) { const float d = oacc[c][r] - mu; var += d*d; }
    var += DPPF(var, 0xB1);
    var += DPPF(var, 0x4E);
    var += __shfl_xor(var, 4);
    var += DPPF(var, 0x128);
    const float rstd = rsqrtf(var * (1.f/64.f) + 1e-5f);
    #pragma unroll
    for (int c = 0; c < 4; ++c) {
      const int ch = hb2 + c*16 + lc;
      const float hn = (oacc[c][r] - mu) * rstd * lnc[c];
      const float xcv = bf2f(xc_lds[s*SXC + ch]);
      q_lds[s*SQ + ch] = f2bf(hn + skc[c]*xcv);   // q_lds dead since B2; own-wave cols
    }
  }
  __syncthreads();   // B6: publish h-part

  // --- coalesced RMW pass: thread owns column ch=tid for all 16 rows ---
  #pragma unroll
  for (int s = 0; s < 16; ++s) {
    const long long og = (long long)(rbase + s*1024)*256 + tid;
    const float szv = bf2f(szh[og]);
    const float hv  = bf2f(q_lds[s*SQ + tid]);
    szh[og] = f2bf(hv * szv);
  }
}

// ---------------------------------------------------------------------------
// Phase 3: down-projection, split-bf16 MFMA — R5/R8 version verbatim
// (reverted: R9's hw-split halved MFMA-per-A-load and regressed +35us,
// confirming the R6 lesson that per-block MFMA:fixed-cost ratio dominates
// dispatch-tail effects in these latency-bound GEMMs).
// ---------------------------------------------------------------------------
__global__ __launch_bounds__(256, 3)
void down_gemm(const ushort_t* __restrict__ hb,
               const ushort_t* __restrict__ wdt_hi, const ushort_t* __restrict__ wdt_lo,
               float* __restrict__ out)
{
  const int tid = threadIdx.x;
  const int hw0 = blockIdx.x * 128;
  const int bt  = blockIdx.z;
  const int bq  = bt >> 4, tq = bt & 15;
  const int rowbase = bt*1024 + hw0;

  const int wv = tid >> 6;
  const int wm = wv >> 1, wn = wv & 1;
  const int ln = tid & 63;
  const int lm = ln & 15;
  const int q  = ln >> 4;

  f32x4 acc[4][4];
  #pragma unroll
  for (int i = 0; i < 4; ++i)
    #pragma unroll
    for (int k = 0; k < 4; ++k) acc[i][k] = (f32x4){0.f, 0.f, 0.f, 0.f};

  #pragma unroll 2
  for (int kc = 0; kc < 256; kc += 32) {
    const int kq = kc + q*8;
    short8 ah[4], al[4];
    #pragma unroll
    for (int mt = 0; mt < 4; ++mt) {
      const int c = wm*64 + mt*16 + lm;
      ah[mt] = *(const short8*)&wdt_hi[c*256 + kq];
      al[mt] = *(const short8*)&wdt_lo[c*256 + kq];
    }
    #pragma unroll
    for (int nt = 0; nt < 4; ++nt) {
      const int n = wn*64 + nt*16 + lm;
      const short8 bf = *(const short8*)&hb[(rowbase + n)*256 + kq];
      #pragma unroll
      for (int mt = 0; mt < 4; ++mt) {
        acc[mt][nt] = __builtin_amdgcn_mfma_f32_16x16x32_bf16(ah[mt], bf, acc[mt][nt], 0, 0, 0);
        acc[mt][nt] = __builtin_amdgcn_mfma_f32_16x16x32_bf16(al[mt], bf, acc[mt][nt], 0, 0, 0);
      }
    }
  }

  #pragma unroll
  for (int mt = 0; mt < 4; ++mt) {
    #pragma unroll
    for (int nt = 0; nt < 4; ++nt) {
      const int hw = hw0 + wn*64 + nt*16 + lm;
      #pragma unroll
      for (int r = 0; r < 4; ++r) {
        const int c = wm*64 + mt*16 + q*4 + r;
        out[((bq*128 + c)*16 + tq)*1024 + hw] = acc[mt][nt][r];
      }
    }
  }
}

// ---------------------------------------------------------------------------
extern "C" void kernel_launch(void* const* d_in, const int* in_sizes, int n_in,
                              void* d_out, int out_size, void* d_ws, size_t ws_size,
                              hipStream_t stream)
{
  const float* x      = (const float*)d_in[0];
  const float* Wup    = (const float*)d_in[1];
  const float* conv_w = (const float*)d_in[2];
  const float* conv_b = (const float*)d_in[3];
  const float* Wq     = (const float*)d_in[4];
  const float* Wk     = (const float*)d_in[5];
  const float* Wv     = (const float*)d_in[6];
  const float* igw    = (const float*)d_in[7];
  const float* igb    = (const float*)d_in[8];
  const float* fgw    = (const float*)d_in[9];
  const float* fgb    = (const float*)d_in[10];
  const float* lnw    = (const float*)d_in[11];
  const float* skipw  = (const float*)d_in[12];
  const float* Wd     = (const float*)d_in[13];
  float* out = (float*)d_out;

  // ws layout: xmb bf16 [131072][256] = 64 MB; szb bf16 = 64 MB (silu(z) in,
  // h_state out); then weight fragments (~0.4 MB).
  ushort_t* xmb    = (ushort_t*)d_ws;
  ushort_t* szb    = xmb + 33554432;
  ushort_t* wt_hi  = (ushort_t*)((char*)d_ws + 134217728);
  ushort_t* wt_lo  = wt_hi + 65536;
  ushort_t* wdt_hi = wt_lo + 65536;
  ushort_t* wdt_lo = wdt_hi + 32768;
  ushort_t* wgf    = wdt_lo + 32768;    // 24*64*8 = 12288 bf16

  prep_w<<<432, 256, 0, stream>>>(Wup, Wd, igw, fgw,
                                  wt_hi, wt_lo, wdt_hi, wdt_lo, wgf);
  up_gemm<<<dim3(8, 4, 128), 256, 0, stream>>>(x, wt_hi, wt_lo, xmb, szb);
  seq_kernel<<<8192, 256, 0, stream>>>(xmb, szb,
                                       conv_w, conv_b, Wq, Wk, Wv,
                                       wgf, igb, fgb, lnw, skipw);
  down_gemm<<<dim3(8, 1, 128), 256, 0, stream>>>(szb, wdt_hi, wdt_lo, out);
}

// Round 13
// 365.202 us; speedup vs baseline: 1.1229x; 1.0119x over previous
//
#include <hip/hip_runtime.h>
#include <hip/hip_bf16.h>
#include <cmath>

// Problem constants: B=8, DIM=128, T=16, H*W=1024, INNER=256, UP2=512,
// NH=4, DH=64, K=4, Bx=8192 sequences, S=16.

typedef __attribute__((ext_vector_type(8))) short short8;
typedef __attribute__((ext_vector_type(4))) short short4v;
typedef __attribute__((ext_vector_type(4))) float f32x4;
typedef unsigned short ushort_t;

static __device__ __forceinline__ float siluf(float v) {
  return v / (1.0f + __expf(-v));
}
static __device__ __forceinline__ float logsigf(float v) {
  return fminf(v, 0.f) - log1pf(__expf(-fabsf(v)));
}
static __device__ __forceinline__ float sel4(float4 w, int idx) {
  float r = w.x;
  r = (idx == 1) ? w.y : r;
  r = (idx == 2) ? w.z : r;
  r = (idx == 3) ? w.w : r;
  return r;
}
static __device__ __forceinline__ ushort_t f2bf(float x) {   // RNE fp32->bf16
  unsigned u = __float_as_uint(x);
  return (ushort_t)((u + 0x7fffu + ((u >> 16) & 1u)) >> 16);
}
static __device__ __forceinline__ float bf2f(ushort_t h) {
  return __uint_as_float(((unsigned)h) << 16);
}
// HW packed RNE fp32->bf16 (v_cvt_pk_bf16_f32); bit-identical to f2bf for
// normal values, 1 VALU op per 2 conversions (vs 3 each scalar).
static __device__ __forceinline__ ushort2 pk2bf(float a, float b) {
  union { __hip_bfloat162 v; ushort2 u; } cv;
  cv.v = __float22bfloat162_rn(make_float2(a, b));
  return cv.u;
}
// DPP lane-exchange replacements for __shfl_xor (VALU-speed, no ds_swizzle
// / lgkmcnt in the dependency chain). quad_perm: xor1=0xB1, xor2=0x4E,
// xor3=0x1B. row_ror:8 (0x128) == xor8 within each 16-lane row. row_shr:N
// (0x110+N) with bound_ctrl=true shifts 0 in -> Hillis-Steele scan stages.
#define DPPF(x, ctrl) \
  __int_as_float(__builtin_amdgcn_mov_dpp(__float_as_int(x), (ctrl), 0xF, 0xF, true))

// ---------------------------------------------------------------------------
// Prep: weight fragments (R10 output-major coalesced-write mapping).
// ---------------------------------------------------------------------------
__global__ __launch_bounds__(256)
void prep_w(const float* __restrict__ Wup, const float* __restrict__ Wd,
            const float* __restrict__ igw, const float* __restrict__ fgw,
            ushort_t* __restrict__ wt_hi, ushort_t* __restrict__ wt_lo,
            ushort_t* __restrict__ wdt_hi, ushort_t* __restrict__ wdt_lo,
            ushort_t* __restrict__ wgf)
{
  const int g = blockIdx.x * 256 + threadIdx.x;
  if (g < 65536) {                      // g = j*128 + c (output-major)
    const int jj = g >> 7, c = g & 127;
    const float w = Wup[c*512 + jj];
    const ushort_t h = f2bf(w);
    wt_hi[g] = h;
    wt_lo[g] = f2bf(w - bf2f(h));
  } else if (g < 98304) {               // g2 = c*256 + j (output-major)
    const int g2 = g - 65536;
    const int c = g2 >> 8, jj = g2 & 255;
    const float w = Wd[jj*128 + c];
    const ushort_t h = f2bf(w);
    wdt_hi[g2] = h;
    wdt_lo[g2] = f2bf(w - bf2f(h));
  } else if (g < 110592) {              // gate fragments
    const int e = g - 98304;            // e = kc*512 + lane*8 + i
    const int kc = e >> 9;
    const int lane = (e >> 3) & 63;
    const int i = e & 7;
    const int n = lane & 15;
    const int kq = kc*32 + (lane >> 4)*8 + i;
    float val = 0.f;
    if (n < 4)      val = igw[kq*4 + n];
    else if (n < 8) val = fgw[kq*4 + (n - 4)];
    wgf[e] = f2bf(val);
  }
}

// ---------------------------------------------------------------------------
// Phase 1: up-projection via split-bf16 MFMA — R5 version verbatim
// (best measured; R0-R6 established this is a robust local floor).
// ---------------------------------------------------------------------------
#define AS 72   // LDS row stride in bf16 (64 + 8 pad)

__global__ __launch_bounds__(256, 3)
void up_gemm(const float* __restrict__ x,
             const ushort_t* __restrict__ wt_hi, const ushort_t* __restrict__ wt_lo,
             ushort_t* __restrict__ xmb, ushort_t* __restrict__ szb)
{
  __shared__ ushort_t sAhi[128*AS];
  __shared__ ushort_t sAlo[128*AS];

  const int tid = threadIdx.x;
  const int hw0 = blockIdx.x * 128;
  const int j0  = blockIdx.y * 128;
  const int bt  = blockIdx.z;
  const int b   = bt >> 4, t = bt & 15;

  const int wv = tid >> 6;
  const int wm = wv >> 1, wn = wv & 1;
  const int ln = tid & 63;
  const int lm = ln & 15;
  const int q  = ln >> 4;

  const int hwL = tid & 127;
  const int cg  = tid >> 7;

  f32x4 acc[4][4];
  #pragma unroll
  for (int i = 0; i < 4; ++i)
    #pragma unroll
    for (int k = 0; k < 4; ++k) acc[i][k] = (f32x4){0.f, 0.f, 0.f, 0.f};

  for (int stage = 0; stage < 2; ++stage) {
    // --- batched staging: issue all 32 loads, then convert ---
    float xv[8][4];
    {
      const float* xb = &x[((b*128 + stage*64)*16 + t)*1024 + hw0 + hwL];
      #pragma unroll
      for (int p = 0; p < 8; ++p) {
        const float* xp = xb + (p*8 + cg*4)*16384;
        xv[p][0] = xp[0];
        xv[p][1] = xp[16384];
        xv[p][2] = xp[32768];
        xv[p][3] = xp[49152];
      }
    }
    #pragma unroll
    for (int p = 0; p < 8; ++p) {
      const int cl = p*8 + cg*4;
      const float v0 = xv[p][0], v1 = xv[p][1], v2 = xv[p][2], v3 = xv[p][3];
      const ushort2 h01 = pk2bf(v0, v1);
      const ushort2 h23 = pk2bf(v2, v3);
      const ushort2 l01 = pk2bf(v0 - bf2f(h01.x), v1 - bf2f(h01.y));
      const ushort2 l23 = pk2bf(v2 - bf2f(h23.x), v3 - bf2f(h23.y));
      *(ushort4*)&sAhi[hwL*AS + cl] = make_ushort4(h01.x, h01.y, h23.x, h23.y);
      *(ushort4*)&sAlo[hwL*AS + cl] = make_ushort4(l01.x, l01.y, l23.x, l23.y);
    }
    __syncthreads();

    #pragma unroll
    for (int s = 0; s < 2; ++s) {
      const int kc = s*32 + q*8;
      const int kg = stage*64 + kc;
      short8 bh[4], bl[4];
      #pragma unroll
      for (int nt = 0; nt < 4; ++nt) {
        const int jr = j0 + wn*64 + nt*16 + lm;
        bh[nt] = *(const short8*)&wt_hi[jr*128 + kg];
        bl[nt] = *(const short8*)&wt_lo[jr*128 + kg];
      }
      #pragma unroll
      for (int mt = 0; mt < 4; ++mt) {
        const int ao = (wm*64 + mt*16 + lm)*AS + kc;
        const short8 ah = *(const short8*)&sAhi[ao];
        const short8 al = *(const short8*)&sAlo[ao];
        #pragma unroll
        for (int nt = 0; nt < 4; ++nt) {
          acc[mt][nt] = __builtin_amdgcn_mfma_f32_16x16x32_bf16(ah, bh[nt], acc[mt][nt], 0, 0, 0);
          acc[mt][nt] = __builtin_amdgcn_mfma_f32_16x16x32_bf16(ah, bl[nt], acc[mt][nt], 0, 0, 0);
          acc[mt][nt] = __builtin_amdgcn_mfma_f32_16x16x32_bf16(al, bh[nt], acc[mt][nt], 0, 0, 0);
        }
      }
    }
    __syncthreads();
  }

  // --- epilogue: direct stores (fastest measured path) ---
  const bool isz = (j0 >= 256);
  #pragma unroll
  for (int mt = 0; mt < 4; ++mt) {
    #pragma unroll
    for (int nt = 0; nt < 4; ++nt) {
      const int jc = j0 + wn*64 + nt*16 + lm;
      #pragma unroll
      for (int r = 0; r < 4; ++r) {
        const int rowg = bt*1024 + hw0 + wm*64 + mt*16 + q*4 + r;
        const float v = acc[mt][nt][r];
        if (!isz) xmb[rowg*256 + jc] = f2bf(v);
        else      szb[rowg*256 + (jc - 256)] = f2bf(siluf(v));
      }
    }
  }
}

// ---------------------------------------------------------------------------
// Phase 2: fused conv + qkv + gates + mLSTM + LN + skip.
// R11: (a) barriers 7->5: gate-finalize + lf-cumsum merged into ONE wave-0
//      phase (DPP row_shr Hillis-Steele scan replaces the 16-iter serial
//      loop by 4 threads); B5 dropped (p_lds is wave-private, lgkmcnt
//      ordering suffices). (b) pk2bf pairing for all bf16 conversions
//      (Phase A, P-write, LN epilogue, RMW): ~300 fewer VALU insts/thread.
// Scan reassociates the fp32 lf cumsum (tree vs serial) -> ~1e-7 absolute
// perturbation; all other value paths bit-identical.
// ---------------------------------------------------------------------------
#define SQ 264    // q/k/v row stride (bf16): 528 B -> 2-way banks (free), 16B-aligned rows
#define SXC 260   // xc row stride (bf16), scalar access only

__global__ __launch_bounds__(256, 4)
void seq_kernel(const ushort_t* __restrict__ xm_ws,
                ushort_t* szh,                    // silu(z) in, h_state out
                const float* __restrict__ conv_w, const float* __restrict__ conv_b,
                const float* __restrict__ Wq, const float* __restrict__ Wk,
                const float* __restrict__ Wv,
                const ushort_t* __restrict__ wgf,
                const float* __restrict__ igb, const float* __restrict__ fgb,
                const float* __restrict__ lnw, const float* __restrict__ skipw)
{
  __shared__ __align__(16) ushort_t q_lds[16*SQ];
  __shared__ __align__(16) ushort_t k_lds[16*SQ];
  __shared__ __align__(16) ushort_t v_lds[16*SQ];
  __shared__ __align__(16) ushort_t xc_lds[16*SXC];
  __shared__ __align__(16) ushort_t p_lds[4*16*36];   // P[h][s][t], stride 36
  __shared__ __align__(16) float s_gpart[512];        // [w][t][8]; later aliased s_lfc[17][4]
  __shared__ float s_ig[64];                          // [t][h]

  const int tid = threadIdx.x;
  const int j   = tid;
  const int l2  = j & 3;
  const int seq = blockIdx.x;
  const int rbase = (seq >> 10) * 16384 + (seq & 1023);

  const int w    = tid >> 6;      // wave = head
  const int ln   = tid & 63;
  const int g    = ln >> 4;       // 16-lane group
  const int lc   = ln & 15;       // lane-in-group (MFMA col / A-row)
  const int hb2  = w * 64;

  // --- weights for headwise qkv (lane-permuted for quad shuffles) ---
  const float4 wq4 = *(const float4*)&Wq[j*4];
  const float4 wk4 = *(const float4*)&Wk[j*4];
  const float4 wv4 = *(const float4*)&Wv[j*4];
  float wqp[4], wkp[4], wvp[4];
  #pragma unroll
  for (int d = 0; d < 4; ++d) {
    const int idx = l2 ^ d;
    wqp[d] = sel4(wq4, idx);
    wkp[d] = sel4(wk4, idx);
    wvp[d] = sel4(wv4, idx);
  }
  const float cw0 = conv_w[j],     cw1 = conv_w[256+j];
  const float cw2 = conv_w[512+j], cw3 = conv_w[768+j];
  const float cb  = conv_b[j];

  // --- Phase A: conv + silu + headwise q,k,v ; 8-deep load pipeline ---
  ushort_t mh[8];
  #pragma unroll
  for (int t = 0; t < 8; ++t)
    mh[t] = xm_ws[(rbase + t*1024)*256 + j];

  float p1 = 0.f, p2 = 0.f, p3 = 0.f;
  #pragma unroll
  for (int t = 0; t < 16; ++t) {
    const float m = bf2f(mh[t & 7]);
    if (t < 8) mh[t & 7] = xm_ws[(rbase + (t+8)*1024)*256 + j];  // refill slot
    const float pre = cw0*p3 + cw1*p2 + cw2*p1 + cw3*m + cb;
    const float x = siluf(pre);
    p3 = p2; p2 = p1; p1 = m;
    const float x1 = DPPF(x, 0xB1), x2 = DPPF(x, 0x4E), x3 = DPPF(x, 0x1B);
    const float m1 = DPPF(m, 0xB1), m2 = DPPF(m, 0x4E), m3 = DPPF(m, 0x1B);
    const float qv = x*wqp[0] + x1*wqp[1] + x2*wqp[2] + x3*wqp[3];
    const float kv = x*wkp[0] + x1*wkp[1] + x2*wkp[2] + x3*wkp[3];
    const float vv = m*wvp[0] + m1*wvp[1] + m2*wvp[2] + m3*wvp[3];
    const ushort2 qk = pk2bf(qv, kv);
    const ushort2 vx = pk2bf(vv, x);
    q_lds [t*SQ  + j] = qk.x;
    k_lds [t*SQ  + j] = qk.y;
    v_lds [t*SQ  + j] = vx.x;
    xc_lds[t*SXC + j] = vx.y;
  }
  __syncthreads();   // B1

  // --- Gates via MFMA: Y[16t x 768] * W[768 x 8(+8 pad)], K-split by wave ---
  f32x4 gacc = (f32x4){0.f, 0.f, 0.f, 0.f};
  #pragma unroll
  for (int c6 = 0; c6 < 6; ++c6) {
    const int kc = w*6 + c6;                        // global K-chunk (wave-uniform)
    const ushort_t* yb = (kc < 8) ? q_lds : (kc < 16) ? k_lds : v_lds;
    const int klocal = (kc & 7)*32;
    const short8 ya = *(const short8*)&yb[lc*SQ + klocal + g*8];
    const short8 wb = *(const short8*)&wgf[(kc*64 + ln)*8];
    gacc = __builtin_amdgcn_mfma_f32_16x16x32_bf16(ya, wb, gacc, 0, 0, 0);
  }
  // QK^T via MFMA (needs only q,k of own head; independent of gates)
  f32x4 qkacc = (f32x4){0.f, 0.f, 0.f, 0.f};
  {
    const short8 qa0 = *(const short8*)&q_lds[lc*SQ + hb2 + g*8];
    const short8 qa1 = *(const short8*)&q_lds[lc*SQ + hb2 + 32 + g*8];
    const short8 kb0 = *(const short8*)&k_lds[lc*SQ + hb2 + g*8];
    const short8 kb1 = *(const short8*)&k_lds[lc*SQ + hb2 + 32 + g*8];
    qkacc = __builtin_amdgcn_mfma_f32_16x16x32_bf16(qa0, kb0, qkacc, 0, 0, 0);
    qkacc = __builtin_amdgcn_mfma_f32_16x16x32_bf16(qa1, kb1, qkacc, 0, 0, 0);
  }
  // store gate partials (cols 0..7 valid)
  if (lc < 8) {
    #pragma unroll
    for (int r = 0; r < 4; ++r)
      s_gpart[w*128 + (g*4 + r)*8 + lc] = gacc[r];
  }
  __syncthreads();   // B2

  // --- merged gate finalize + lf cumulative scan (single wave 0) ---
  // Alias-safe: one wave; all s_gpart reads issue (and are waited on)
  // before any s_lfc (alias) write in the same instruction stream.
  float* s_lfc = s_gpart;        // alias: [17][4]
  if (tid < 64) {
    const int t = tid & 15, h = tid >> 4;
    const float si = s_gpart[t*8 + h]       + s_gpart[128 + t*8 + h]
                   + s_gpart[256 + t*8 + h] + s_gpart[384 + t*8 + h];
    const float sf = s_gpart[t*8 + 4 + h]       + s_gpart[128 + t*8 + 4 + h]
                   + s_gpart[256 + t*8 + 4 + h] + s_gpart[384 + t*8 + 4 + h];
    s_ig[t*4 + h] = si + igb[h];
    float lf = logsigf(sf + fgb[h]);
    // inclusive Hillis-Steele scan over t (16-lane row; bound_ctrl -> 0 in)
    lf += DPPF(lf, 0x111);   // row_shr:1
    lf += DPPF(lf, 0x112);   // row_shr:2
    lf += DPPF(lf, 0x114);   // row_shr:4
    lf += DPPF(lf, 0x118);   // row_shr:8
    s_lfc[(t+1)*4 + h] = lf;
    if (t == 0) s_lfc[h] = 0.f;
  }
  __syncthreads();   // B3 (was B3+B4)

  // --- decay + normalizer in C-layout: lane holds rows s=g*4+r, col t=lc ---
  {
    const int tcol = lc;
    const float lfc_t1 = s_lfc[(tcol+1)*4 + w];
    const float igt    = s_ig[tcol*4 + w];
    float ld[4], mloc[4];
    #pragma unroll
    for (int r = 0; r < 4; ++r) {
      const int s = g*4 + r;
      const float lfs = s_lfc[(s+1)*4 + w];
      ld[r] = (tcol <= s) ? (lfs - lfc_t1 + igt) : -INFINITY;
      mloc[r] = ld[r];
    }
    // butterfly max over 16-lane groups: stages 1,2,4,8 (1,2,8 via DPP)
    #pragma unroll
    for (int r = 0; r < 4; ++r) {
      mloc[r] = fmaxf(mloc[r], DPPF(mloc[r], 0xB1));
      mloc[r] = fmaxf(mloc[r], DPPF(mloc[r], 0x4E));
      mloc[r] = fmaxf(mloc[r], __shfl_xor(mloc[r], 4));
      mloc[r] = fmaxf(mloc[r], DPPF(mloc[r], 0x128));
    }
    float cs[4], rsum[4];
    #pragma unroll
    for (int r = 0; r < 4; ++r) {
      const int s = g*4 + r;
      cs[r] = (tcol <= s) ? (qkacc[r] * 0.125f) * __expf(ld[r] - mloc[r]) : 0.f;
      rsum[r] = cs[r];
    }
    // butterfly sum, same stage order as before -> bit-identical
    #pragma unroll
    for (int r = 0; r < 4; ++r) {
      rsum[r] += DPPF(rsum[r], 0xB1);
      rsum[r] += DPPF(rsum[r], 0x4E);
      rsum[r] += __shfl_xor(rsum[r], 4);
      rsum[r] += DPPF(rsum[r], 0x128);
    }
    float pvv[4];
    #pragma unroll
    for (int r = 0; r < 4; ++r) {
      const float denom = fmaxf(fabsf(rsum[r]), __expf(-mloc[r])) + 1e-6f;
      pvv[r] = cs[r] / denom;
    }
    const ushort2 p01 = pk2bf(pvv[0], pvv[1]);
    const ushort2 p23 = pk2bf(pvv[2], pvv[3]);
    p_lds[(w*16 + g*4 + 0)*36 + tcol] = p01.x;
    p_lds[(w*16 + g*4 + 1)*36 + tcol] = p01.y;
    p_lds[(w*16 + g*4 + 2)*36 + tcol] = p23.x;
    p_lds[(w*16 + g*4 + 3)*36 + tcol] = p23.y;
  }
  // NO barrier here: p_lds rows [w*16, w*16+16) are written and read by the
  // SAME wave; compiler-inserted lgkmcnt orders the ds ops.

  // --- PV via MFMA: O[16s x 64d] = P[16 x 32pad] x V[32pad x 64] ---
  f32x4 oacc[4];
  #pragma unroll
  for (int c = 0; c < 4; ++c) oacc[c] = (f32x4){0.f, 0.f, 0.f, 0.f};
  {
    const int tb = g*8;
    short8 pa = (short8){0,0,0,0,0,0,0,0};
    if (tb < 16) {
      const short4v plo = *(const short4v*)&p_lds[(w*16 + lc)*36 + tb];
      const short4v phi = *(const short4v*)&p_lds[(w*16 + lc)*36 + tb + 4];
      pa[0]=plo[0]; pa[1]=plo[1]; pa[2]=plo[2]; pa[3]=plo[3];
      pa[4]=phi[0]; pa[5]=phi[1]; pa[6]=phi[2]; pa[7]=phi[3];
    }
    #pragma unroll
    for (int c = 0; c < 4; ++c) {
      short8 vb;
      #pragma unroll
      for (int i = 0; i < 8; ++i)
        vb[i] = (short)v_lds[((tb + i) & 15)*SQ + hb2 + c*16 + lc];  // garbage ok when tb>=16 (A=0)
      oacc[c] = __builtin_amdgcn_mfma_f32_16x16x32_bf16(pa, vb, oacc[c], 0, 0, 0);
    }
  }

  // --- LN over DH=64 + epilogue; lane holds O[s=g*4+r][d=c*16+lc] ---
  float lnc[4], skc[4];
  #pragma unroll
  for (int c = 0; c < 4; ++c) {
    const int ch = hb2 + c*16 + lc;
    lnc[c] = lnw[ch];
    skc[c] = skipw[ch];
  }
  #pragma unroll
  for (int r = 0; r < 4; ++r) {
    const int s = g*4 + r;
    float tot = oacc[0][r] + oacc[1][r] + oacc[2][r] + oacc[3][r];
    tot += DPPF(tot, 0xB1);
    tot += DPPF(tot, 0x4E);
    tot += __shfl_xor(tot, 4);
    tot += DPPF(tot, 0x128);
    const float mu = tot * (1.f/64.f);
    float var = 0.f;
    #pragma unroll
    for (int c = 0; c < 4; ++c) { const float d = oacc[c][r] - mu; var += d*d; }
    var += DPPF(var, 0xB1);
    var += DPPF(var, 0x4E);
    var += __shfl_xor(var, 4);
    var += DPPF(var, 0x128);
    const float rstd = rsqrtf(var * (1.f/64.f) + 1e-5f);
    float hval[4];
    #pragma unroll
    for (int c = 0; c < 4; ++c) {
      const int ch = hb2 + c*16 + lc;
      const float hn = (oacc[c][r] - mu) * rstd * lnc[c];
      const float xcv = bf2f(xc_lds[s*SXC + ch]);
      hval[c] = hn + skc[c]*xcv;
    }
    const ushort2 h01 = pk2bf(hval[0], hval[1]);
    const ushort2 h23 = pk2bf(hval[2], hval[3]);
    q_lds[s*SQ + hb2 + 0*16 + lc] = h01.x;   // q_lds dead since B2; own-wave cols
    q_lds[s*SQ + hb2 + 1*16 + lc] = h01.y;
    q_lds[s*SQ + hb2 + 2*16 + lc] = h23.x;
    q_lds[s*SQ + hb2 + 3*16 + lc] = h23.y;
  }
  __syncthreads();   // B4': publish h-part (cross-wave columns in RMW pass)

  // --- coalesced RMW pass: thread owns column ch=tid for all 16 rows ---
  #pragma unroll
  for (int s = 0; s < 16; s += 2) {
    const long long og0 = (long long)(rbase + s*1024)*256 + tid;
    const long long og1 = (long long)(rbase + (s+1)*1024)*256 + tid;
    const float szv0 = bf2f(szh[og0]);
    const float szv1 = bf2f(szh[og1]);
    const float hv0  = bf2f(q_lds[s*SQ + tid]);
    const float hv1  = bf2f(q_lds[(s+1)*SQ + tid]);
    const ushort2 hs = pk2bf(hv0 * szv0, hv1 * szv1);
    szh[og0] = hs.x;
    szh[og1] = hs.y;
  }
}

// ---------------------------------------------------------------------------
// Phase 3: down-projection, split-bf16 MFMA — R5/R8 version verbatim
// (R9's hw-split regressed +35us: per-block MFMA:fixed-cost ratio dominates
// dispatch-tail effects in these latency-bound GEMMs).
// ---------------------------------------------------------------------------
__global__ __launch_bounds__(256, 3)
void down_gemm(const ushort_t* __restrict__ hb,
               const ushort_t* __restrict__ wdt_hi, const ushort_t* __restrict__ wdt_lo,
               float* __restrict__ out)
{
  const int tid = threadIdx.x;
  const int hw0 = blockIdx.x * 128;
  const int bt  = blockIdx.z;
  const int bq  = bt >> 4, tq = bt & 15;
  const int rowbase = bt*1024 + hw0;

  const int wv = tid >> 6;
  const int wm = wv >> 1, wn = wv & 1;
  const int ln = tid & 63;
  const int lm = ln & 15;
  const int q  = ln >> 4;

  f32x4 acc[4][4];
  #pragma unroll
  for (int i = 0; i < 4; ++i)
    #pragma unroll
    for (int k = 0; k < 4; ++k) acc[i][k] = (f32x4){0.f, 0.f, 0.f, 0.f};

  #pragma unroll 2
  for (int kc = 0; kc < 256; kc += 32) {
    const int kq = kc + q*8;
    short8 ah[4], al[4];
    #pragma unroll
    for (int mt = 0; mt < 4; ++mt) {
      const int c = wm*64 + mt*16 + lm;
      ah[mt] = *(const short8*)&wdt_hi[c*256 + kq];
      al[mt] = *(const short8*)&wdt_lo[c*256 + kq];
    }
    #pragma unroll
    for (int nt = 0; nt < 4; ++nt) {
      const int n = wn*64 + nt*16 + lm;
      const short8 bf = *(const short8*)&hb[(rowbase + n)*256 + kq];
      #pragma unroll
      for (int mt = 0; mt < 4; ++mt) {
        acc[mt][nt] = __builtin_amdgcn_mfma_f32_16x16x32_bf16(ah[mt], bf, acc[mt][nt], 0, 0, 0);
        acc[mt][nt] = __builtin_amdgcn_mfma_f32_16x16x32_bf16(al[mt], bf, acc[mt][nt], 0, 0, 0);
      }
    }
  }

  #pragma unroll
  for (int mt = 0; mt < 4; ++mt) {
    #pragma unroll
    for (int nt = 0; nt < 4; ++nt) {
      const int hw = hw0 + wn*64 + nt*16 + lm;
      #pragma unroll
      for (int r = 0; r < 4; ++r) {
        const int c = wm*64 + mt*16 + q*4 + r;
        out[((bq*128 + c)*16 + tq)*1024 + hw] = acc[mt][nt][r];
      }
    }
  }
}

// ---------------------------------------------------------------------------
extern "C" void kernel_launch(void* const* d_in, const int* in_sizes, int n_in,
                              void* d_out, int out_size, void* d_ws, size_t ws_size,
                              hipStream_t stream)
{
  const float* x      = (const float*)d_in[0];
  const float* Wup    = (const float*)d_in[1];
  const float* conv_w = (const float*)d_in[2];
  const float* conv_b = (const float*)d_in[3];
  const float* Wq     = (const float*)d_in[4];
  const float* Wk     = (const float*)d_in[5];
  const float* Wv     = (const float*)d_in[6];
  const float* igw    = (const float*)d_in[7];
  const float* igb    = (const float*)d_in[8];
  const float* fgw    = (const float*)d_in[9];
  const float* fgb    = (const float*)d_in[10];
  const float* lnw    = (const float*)d_in[11];
  const float* skipw  = (const float*)d_in[12];
  const float* Wd     = (const float*)d_in[13];
  float* out = (float*)d_out;

  // ws layout: xmb bf16 [131072][256] = 64 MB; szb bf16 = 64 MB (silu(z) in,
  // h_state out); then weight fragments (~0.4 MB).
  ushort_t* xmb    = (ushort_t*)d_ws;
  ushort_t* szb    = xmb + 33554432;
  ushort_t* wt_hi  = (ushort_t*)((char*)d_ws + 134217728);
  ushort_t* wt_lo  = wt_hi + 65536;
  ushort_t* wdt_hi = wt_lo + 65536;
  ushort_t* wdt_lo = wdt_hi + 32768;
  ushort_t* wgf    = wdt_lo + 32768;    // 24*64*8 = 12288 bf16

  prep_w<<<432, 256, 0, stream>>>(Wup, Wd, igw, fgw,
                                  wt_hi, wt_lo, wdt_hi, wdt_lo, wgf);
  up_gemm<<<dim3(8, 4, 128), 256, 0, stream>>>(x, wt_hi, wt_lo, xmb, szb);
  seq_kernel<<<8192, 256, 0, stream>>>(xmb, szb,
                                       conv_w, conv_b, Wq, Wk, Wv,
                                       wgf, igb, fgb, lnw, skipw);
  down_gemm<<<dim3(8, 1, 128), 256, 0, stream>>>(szb, wdt_hi, wdt_lo, out);
}